// Round 7
// baseline (500.639 us; speedup 1.0000x reference)
//
#include <hip/hip_runtime.h>
#include <hip/hip_fp16.h>

#define M_DIM 16384
#define K_DIM 2048
#define N_DIM 2048

#define BM 128
#define BN 128
#define BK 128
#define NT (K_DIM / BK)

typedef int int4v  __attribute__((ext_vector_type(4)));
typedef int int16v __attribute__((ext_vector_type(16)));

__device__ __forceinline__ void gl_lds16(const void* g, void* l) {
    __builtin_amdgcn_global_load_lds(
        (const __attribute__((address_space(1))) void*)g,
        (__attribute__((address_space(3))) void*)l,
        16, 0, 0);
}

__device__ __forceinline__ int pack4(int4v v) {
    return (v[0] & 255) | ((v[1] & 255) << 8) | ((v[2] & 255) << 16) | (v[3] << 24);
}

// pack low bytes of 4 int32 -> 1 int, via v_perm_b32 (3 ops vs 7)
__device__ __forceinline__ int packb0(int4v v) {
    unsigned t0 = __builtin_amdgcn_perm((unsigned)v[1], (unsigned)v[0], 0x00000400u);
    unsigned t1 = __builtin_amdgcn_perm((unsigned)v[3], (unsigned)v[2], 0x00000400u);
    return (int)__builtin_amdgcn_perm(t1, t0, 0x05040100u);
}

// weight: int32 [K,N] -> int8 WT [N,K] (transpose + pack), 64x64 tiles via LDS
__global__ void wt_pack_kernel(const int* __restrict__ w, char* __restrict__ wt) {
    __shared__ char tile[64][68];
    int b  = blockIdx.x;
    int k0 = (b & 31) * 64;
    int n0 = (b >> 5) * 64;
    int t  = threadIdx.x;
    int r  = t >> 2;
    int c  = (t & 3) * 16;

    const int* src = w + (size_t)(k0 + r) * N_DIM + n0 + c;
    int4v a = *(const int4v*)(src + 0);
    int4v bb = *(const int4v*)(src + 4);
    int4v cc = *(const int4v*)(src + 8);
    int4v dd = *(const int4v*)(src + 12);
    *(int*)&tile[r][c + 0]  = pack4(a);
    *(int*)&tile[r][c + 4]  = pack4(bb);
    *(int*)&tile[r][c + 8]  = pack4(cc);
    *(int*)&tile[r][c + 12] = pack4(dd);
    __syncthreads();

    char buf[16];
#pragma unroll
    for (int j = 0; j < 16; ++j) buf[j] = tile[c + j][r];
    *(int4v*)(wt + (size_t)(n0 + r) * K_DIM + k0 + c) = *(int4v*)buf;
}

// GEMM with FUSED A-pack: A int32 [M,K] read directly (no pack_x kernel),
// BT int8 [N,K] -> C fp32 [M,N] (+bias).
// R0 geometry (the best measured): 128x128 tile, BK=128, 256 thr = 4 waves
// (2x2), wave tile 64x64 = acc[2][2]. 2 blocks/CU (LDS 48 KB).
// A staging is reg-staged (T14 -- forced, since global_load_lds can't
// convert): per tile, thread t loads 64 contiguous int32 (16 dwordx4, row
// t>>1, half t&1), packs low bytes via v_perm (16 packb0), ds_writes 4
// swizzled b128 chunks. Loads issue at tile top -> latency hidden under the
// 32-MFMA compute span; pack is reg-only and overlaps the barrier approach.
// B stays gl_lds16 double-buffered (pre-swizzled source, unchanged).
// Per-tile: { issue A-loads(t+1) + B gl_lds(t+1); compute(t); pack;
//             sync; ds_write A(t+1) -> Asm; sync }
// LDS layout (16B slots, 8 chunks/row, XOR): slot = r*8 + (c ^ (r&7)); read
// ch = (2ks+khl)^l7 -> distinct slot%8 per 8-lane group (conflict-floor).
// Grid is nt-fastest: the 16 blocks sharing an A panel run concurrently ->
// A (128 MB int32) fetched from HBM once, re-reads hit L2/L3.
__global__ __launch_bounds__(256, 2)
void gemm_i8_kernel(const int* __restrict__ A32, const char* __restrict__ BT,
                    const __half* __restrict__ bias, float* __restrict__ C) {
    __shared__ char Asm[BM * BK];      // 16 KB (single buffer)
    __shared__ char Bsm[2][BN * BK];   // 2 x 16 KB

    const int bid = blockIdx.x;
    const int nt = bid & 15;            // n fastest: A-panel sharers co-resident
    const int mt = bid >> 4;
    const int R0 = mt * BM, C0 = nt * BN;

    const int t = threadIdx.x;
    const int lane = t & 63;
    const int w = t >> 6;
    const int wm = w & 1, wn = w >> 1;
    const int l31 = lane & 31, l7 = lane & 7, khl = lane >> 5;

    int16v acc[2][2];
#pragma unroll
    for (int i = 0; i < 2; ++i)
#pragma unroll
        for (int j = 0; j < 2; ++j) acc[i][j] = (int16v)0;

    // A: thread t stages row ar = t>>1, 64 int32 at col ah*64 (contiguous 256 B)
    const int ar = t >> 1, ah = t & 1;
    const int* asrc = A32 + (size_t)(R0 + ar) * K_DIM + ah * 64;
    int awb[4];   // swizzled ds_write byte offsets for chunks c = ah*4+q
#pragma unroll
    for (int q = 0; q < 4; ++q)
        awb[q] = (ar * 8 + (((ah * 4 + q) ^ (ar & 7)))) * 16;

    // B staging: slots t + 256j; slot s -> row s>>3, stored chunk s&7,
    // global chunk cg = (s&7)^(row&7)  (pre-swizzled source, linear LDS dest)
    unsigned boff[4];
    int ldst[4];
#pragma unroll
    for (int j = 0; j < 4; ++j) {
        int s = t + j * 256;
        int r = s >> 3;
        int cg = (s & 7) ^ (r & 7);
        boff[j] = (unsigned)(C0 + r) * K_DIM + cg * 16;
        ldst[j] = s * 16;
    }

    // fragment row-slot bases (row*8); row&7 == l7 (bases are mult. of 32)
    int arow[2], brow[2];
#pragma unroll
    for (int i = 0; i < 2; ++i) arow[i] = (wm * 64 + i * 32 + l31) * 8;
#pragma unroll
    for (int j = 0; j < 2; ++j) brow[j] = (wn * 64 + j * 32 + l31) * 8;

    int4v av[16];

    // prologue: tile 0 -> Asm, Bsm[0]
#pragma unroll
    for (int i = 0; i < 16; ++i) av[i] = *(const int4v*)(asrc + 4 * i);
#pragma unroll
    for (int j = 0; j < 4; ++j) gl_lds16(BT + boff[j], &Bsm[0][ldst[j]]);
    {
        int4v pw[4];
#pragma unroll
        for (int q = 0; q < 4; ++q)
#pragma unroll
            for (int e = 0; e < 4; ++e) pw[q][e] = packb0(av[4 * q + e]);
#pragma unroll
        for (int q = 0; q < 4; ++q) *(int4v*)&Asm[awb[q]] = pw[q];
    }
    __syncthreads();   // drains B vmcnt + A lds writes

    for (int kt = 0; kt < NT; ++kt) {
        const int cur = kt & 1;
        if (kt + 1 < NT) {
            const int kn = (kt + 1) * BK;
#pragma unroll
            for (int i = 0; i < 16; ++i)
                av[i] = *(const int4v*)(asrc + kn + 4 * i);
#pragma unroll
            for (int j = 0; j < 4; ++j)
                gl_lds16(BT + boff[j] + kn, &Bsm[cur ^ 1][ldst[j]]);
        }
#pragma unroll
        for (int ks = 0; ks < 4; ++ks) {
            const int ch = (2 * ks + khl) ^ l7;
            int4v af[2], bf[2];
#pragma unroll
            for (int i = 0; i < 2; ++i)
                af[i] = *(const int4v*)&Asm[(arow[i] + ch) * 16];
#pragma unroll
            for (int j = 0; j < 2; ++j)
                bf[j] = *(const int4v*)&Bsm[cur][(brow[j] + ch) * 16];
#pragma unroll
            for (int i = 0; i < 2; ++i)
#pragma unroll
                for (int j = 0; j < 2; ++j)
                    acc[i][j] = __builtin_amdgcn_mfma_i32_32x32x32_i8(
                        af[i], bf[j], acc[i][j], 0, 0, 0);
        }
        if (kt + 1 < NT) {
            int4v pw[4];   // reg-only pack (compiler inserts the av vmcnt)
#pragma unroll
            for (int q = 0; q < 4; ++q)
#pragma unroll
                for (int e = 0; e < 4; ++e) pw[q][e] = packb0(av[4 * q + e]);
            __syncthreads();              // all waves done reading Asm(kt); B landed
#pragma unroll
            for (int q = 0; q < 4; ++q) *(int4v*)&Asm[awb[q]] = pw[q];
            __syncthreads();              // A(kt+1) visible
        }
    }

    // epilogue: C/D layout col=lane&31, row=(reg&3)+8*(reg>>2)+4*(lane>>5)
    const int col = l31;
    const int rbase = khl * 4;
#pragma unroll
    for (int j = 0; j < 2; ++j) {
        const int cn = C0 + wn * 64 + j * 32 + col;
        const float bv = __half2float(bias[cn]);
#pragma unroll
        for (int i = 0; i < 2; ++i) {
            const int rm = R0 + wm * 64 + i * 32 + rbase;
#pragma unroll
            for (int reg = 0; reg < 16; ++reg) {
                const int row = rm + (reg & 3) + 8 * (reg >> 2);
                C[(size_t)row * N_DIM + cn] = (float)acc[i][j][reg] + bv;
            }
        }
    }
}

extern "C" void kernel_launch(void* const* d_in, const int* in_sizes, int n_in,
                              void* d_out, int out_size, void* d_ws, size_t ws_size,
                              hipStream_t stream) {
    const int* x = (const int*)d_in[0];
    const int* wgt = (const int*)d_in[1];
    const __half* bias = (const __half*)d_in[2];
    float* out = (float*)d_out;

    char* wt = (char*)d_ws;   // 4 MiB packed W^T (pack_x is fused into the gemm)

    wt_pack_kernel<<<(K_DIM / 64) * (N_DIM / 64), 256, 0, stream>>>(wgt, wt);
    gemm_i8_kernel<<<(M_DIM / BM) * (N_DIM / BN), 256, 0, stream>>>(x, wt, bias, out);
}